// Round 1
// baseline (849.224 us; speedup 1.0000x reference)
//
#include <hip/hip_runtime.h>
#include <hip/hip_bf16.h>
#include <stdint.h>

// ---- problem constants ----
#define C_DIM 1024
#define H_DIM 16
#define K_DIM 64
#define T_CH 128
#define TT_DIM 4096
#define B_DIM 4
#define N_CH 32
#define M_ROWS 16384  // B*TT

typedef __attribute__((ext_vector_type(8))) __bf16 bf16x8;
typedef __attribute__((ext_vector_type(4))) float floatx4;

__device__ __forceinline__ float bf2f(ushort u) {
  union { uint32_t i; float f; } v; v.i = ((uint32_t)u) << 16; return v.f;
}
__device__ __forceinline__ ushort f2bf(float f) {
  union { float f; uint32_t i; } v; v.f = f;
  return (ushort)((v.i + 0x7fffu + ((v.i >> 16) & 1u)) >> 16);  // RNE
}

#define GLOAD_LDS16(g, l)                                                     \
  __builtin_amdgcn_global_load_lds(                                           \
      (const __attribute__((address_space(1))) void*)(g),                     \
      (__attribute__((address_space(3))) void*)(l), 16, 0, 0)

// ============================================================
// 1) time-shift mix: xr/xk/xv/xg (bf16) from x (fp32)
// ============================================================
__global__ __launch_bounds__(256) void mix_kernel(
    const float* __restrict__ x,
    const float* __restrict__ mk, const float* __restrict__ mv,
    const float* __restrict__ mr, const float* __restrict__ mg,
    ushort* __restrict__ xr, ushort* __restrict__ xk,
    ushort* __restrict__ xv, ushort* __restrict__ xg) {
  long idx = (long)blockIdx.x * 256 + threadIdx.x;
  long e = idx * 4;
  int c = (int)(e & (C_DIM - 1));
  long row = e >> 10;
  int t = (int)(row & (TT_DIM - 1));
  floatx4 xc = *(const floatx4*)(x + e);
  floatx4 xp = {0.f, 0.f, 0.f, 0.f};
  if (t != 0) xp = *(const floatx4*)(x + e - C_DIM);
  floatx4 d = xc - xp;
  floatx4 vk = *(const floatx4*)(mk + c);
  floatx4 vv = *(const floatx4*)(mv + c);
  floatx4 vr = *(const floatx4*)(mr + c);
  floatx4 vg = *(const floatx4*)(mg + c);
  floatx4 ok = xp + d * vk;
  floatx4 ov = xp + d * vv;
  floatx4 orr = xp + d * vr;
  floatx4 og = xp + d * vg;
  union { ushort u[4]; uint2 q; } pk;
#define ST(dst, val)                                                          \
  pk.u[0] = f2bf(val.x); pk.u[1] = f2bf(val.y);                               \
  pk.u[2] = f2bf(val.z); pk.u[3] = f2bf(val.w);                               \
  *(uint2*)((dst) + e) = pk.q;
  ST(xk, ok) ST(xv, ov) ST(xr, orr) ST(xg, og)
#undef ST
}

// ============================================================
// 2) fp32 -> bf16 weight conversion (5 weights concatenated)
// ============================================================
__global__ __launch_bounds__(256) void wconv_kernel(
    const float* __restrict__ w0, const float* __restrict__ w1,
    const float* __restrict__ w2, const float* __restrict__ w3,
    const float* __restrict__ w4, ushort* __restrict__ o) {
  long idx = (long)blockIdx.x * 256 + threadIdx.x;
  long e = idx * 4;
  int wi = (int)(e >> 20);
  long off = e & ((1L << 20) - 1);
  const float* src = wi == 0 ? w0 : wi == 1 ? w1 : wi == 2 ? w2 : wi == 3 ? w3 : w4;
  floatx4 vv = *(const floatx4*)(src + off);
  union { ushort u[4]; uint2 q; } pk;
  pk.u[0] = f2bf(vv.x); pk.u[1] = f2bf(vv.y);
  pk.u[2] = f2bf(vv.z); pk.u[3] = f2bf(vv.w);
  *(uint2*)(o + e) = pk.q;
}

// ============================================================
// 3) bf16 GEMM: C[M,N] = A[M,K] * Bt[N,K]^T  (m97 structure)
//    M=16384, N=K=1024 fixed. EPI: 0=bf16, 1=bf16+silu, 2=fp32
// ============================================================
template <int EPI>
__global__ __launch_bounds__(256) void gemm_bt(
    const ushort* __restrict__ A, const ushort* __restrict__ Bt,
    void* __restrict__ Cout) {
  __shared__ __align__(16) ushort As[128 * 32];
  __shared__ __align__(16) ushort Bs[128 * 32];
  int tid = threadIdx.x;
  int lane = tid & 63, w = tid >> 6;
  int q = lane >> 4, l16 = lane & 15;
  int wm = w >> 1, wn = w & 1;
  int bn = blockIdx.x, bm = blockIdx.y;

  const ushort* gA0 = A + (long)(bm * 128 + w * 16 + (lane >> 2)) * C_DIM + (lane & 3) * 8;
  const ushort* gA1 = gA0 + 64 * C_DIM;
  const ushort* gB0 = Bt + (long)(bn * 128 + w * 16 + (lane >> 2)) * C_DIM + (lane & 3) * 8;
  const ushort* gB1 = gB0 + 64 * C_DIM;
  // wave-uniform LDS bases (hw adds lane*16B)
  ushort* lA0 = As + (w * 16) * 32;
  ushort* lA1 = As + (64 + w * 16) * 32;
  ushort* lB0 = Bs + (w * 16) * 32;
  ushort* lB1 = Bs + (64 + w * 16) * 32;

  floatx4 acc[4][4] = {};

  for (int k0 = 0; k0 < C_DIM; k0 += 32) {
    __syncthreads();
    GLOAD_LDS16(gA0, lA0);
    GLOAD_LDS16(gA1, lA1);
    GLOAD_LDS16(gB0, lB0);
    GLOAD_LDS16(gB1, lB1);
    gA0 += 32; gA1 += 32; gB0 += 32; gB1 += 32;
    __syncthreads();
    bf16x8 af[4], bfv[4];
#pragma unroll
    for (int i = 0; i < 4; i++)
      af[i] = *(const bf16x8*)&As[(wm * 64 + i * 16 + l16) * 32 + q * 8];
#pragma unroll
    for (int i = 0; i < 4; i++)
      bfv[i] = *(const bf16x8*)&Bs[(wn * 64 + i * 16 + l16) * 32 + q * 8];
#pragma unroll
    for (int mi = 0; mi < 4; mi++)
#pragma unroll
      for (int ni = 0; ni < 4; ni++)
        acc[mi][ni] = __builtin_amdgcn_mfma_f32_16x16x32_bf16(
            af[mi], bfv[ni], acc[mi][ni], 0, 0, 0);
  }

  int row0 = bm * 128 + wm * 64 + q * 4;
  int col0 = bn * 128 + wn * 64 + l16;
#pragma unroll
  for (int mi = 0; mi < 4; mi++)
#pragma unroll
    for (int ni = 0; ni < 4; ni++)
#pragma unroll
      for (int rg = 0; rg < 4; rg++) {
        long off = (long)(row0 + mi * 16 + rg) * C_DIM + col0 + ni * 16;
        float val = acc[mi][ni][rg];
        if (EPI == 1) val = val / (1.f + expf(-val));  // silu
        if (EPI == 2)
          ((float*)Cout)[off] = val;
        else
          ((ushort*)Cout)[off] = f2bf(val);
      }
}

// ============================================================
// 4) fused RWKV5 chunked attention + GroupNorm + *g  -> gy (bf16)
//    one block per (b,h); sequential scan over 32 chunks;
//    state Z[v,k] = S^T kept fp32 in LDS.
// ============================================================
__global__ __launch_bounds__(256) void rwkv_attn(
    const ushort* __restrict__ rB, const ushort* __restrict__ kB,
    const ushort* __restrict__ vB, const ushort* __restrict__ gBuf,
    const float* __restrict__ td, const float* __restrict__ tf,
    const float* __restrict__ lnw, const float* __restrict__ lnb,
    ushort* __restrict__ gy) {
  __shared__ __align__(16) ushort rr_s[128 * 72];   // rr row-major, pad 72
  __shared__ __align__(16) ushort kk_s[128 * 72];   // kk row-major
  __shared__ __align__(16) ushort vt_s[64 * 136];   // vv^T  [v][j]
  __shared__ __align__(16) ushort kwt_s[64 * 136];  // (kk*wk)^T [k][j]
  __shared__ __align__(16) ushort p_s[128 * 136];   // att2 bf16 [i][j]
  __shared__ __align__(16) float z_s[64 * 68];      // state Z=S^T fp32 [v][k]

  int bh = blockIdx.x;
  int b = bh >> 4, h = bh & 15;
  int tid = threadIdx.x;
  int lane = tid & 63, w = tid >> 6;
  int q = lane >> 4, l16 = lane & 15;

  float etd = expf(td[h]);           // log(decay) = -etd  (exact)
  float u = tf[h];
  float wsf = expf(-128.f * etd);    // decay^T

  for (int i = tid; i < 64 * 68; i += 256) z_s[i] = 0.f;

  long base = ((long)b * TT_DIM) * C_DIM + h * K_DIM;

  for (int n = 0; n < N_CH; n++) {
    __syncthreads();  // prev chunk fully consumed
    long cbase = base + (long)n * T_CH * C_DIM;
#pragma unroll
    for (int it = 0; it < 4; it++) {
      int chunk = it * 256 + tid;      // 0..1023
      int row = chunk >> 3;            // 0..127 (time within chunk)
      int cc = (chunk & 7) * 8;        // 0..56  (head-dim chunk)
      long ga = cbase + (long)row * C_DIM + cc;
      uint4 rv = *(const uint4*)(rB + ga);
      *(uint4*)&rr_s[row * 72 + cc] = rv;
      uint4 kv4 = *(const uint4*)(kB + ga);
      *(uint4*)&kk_s[row * 72 + cc] = kv4;
      uint4 vv4 = *(const uint4*)(vB + ga);
      float wkj = expf(-(float)(T_CH - 1 - row) * etd);  // decay^(T-1-j)
      const ushort* kp = (const ushort*)&kv4;
      const ushort* vp = (const ushort*)&vv4;
#pragma unroll
      for (int e2 = 0; e2 < 8; e2++) {
        kwt_s[(cc + e2) * 136 + row] = f2bf(bf2f(kp[e2]) * wkj);
        vt_s[(cc + e2) * 136 + row] = vp[e2];
      }
    }
    __syncthreads();

    // ---------- phase 1 ----------
    // att = rr @ kk^T on wave's 64x64 tile
    floatx4 accA[4][4] = {};
    int ai0 = (w >> 1) * 64, aj0 = (w & 1) * 64;
#pragma unroll
    for (int ks = 0; ks < 64; ks += 32) {
      bf16x8 af[4], bk2[4];
#pragma unroll
      for (int i = 0; i < 4; i++)
        af[i] = *(const bf16x8*)&rr_s[(ai0 + i * 16 + l16) * 72 + q * 8 + ks];
#pragma unroll
      for (int j = 0; j < 4; j++)
        bk2[j] = *(const bf16x8*)&kk_s[(aj0 + j * 16 + l16) * 72 + q * 8 + ks];
#pragma unroll
      for (int mi = 0; mi < 4; mi++)
#pragma unroll
        for (int nj = 0; nj < 4; nj++)
          accA[mi][nj] = __builtin_amdgcn_mfma_f32_16x16x32_bf16(
              af[mi], bk2[nj], accA[mi][nj], 0, 0, 0);
    }
    // apply w_mat, store P (bf16) to LDS
#pragma unroll
    for (int mi = 0; mi < 4; mi++)
#pragma unroll
      for (int nj = 0; nj < 4; nj++)
#pragma unroll
        for (int rg = 0; rg < 4; rg++) {
          int i = ai0 + mi * 16 + q * 4 + rg;
          int j = aj0 + nj * 16 + l16;
          float wv = 0.f;
          if (i > j) wv = expf(-(float)(i - j - 1) * etd);
          else if (i == j) wv = u;
          p_s[i * 136 + j] = f2bf(accA[mi][nj][rg] * wv);
        }
    // accZ = vv^T @ (kk*wk)  -> new-state contribution, wave owns v-rows w*16..
    floatx4 accZ[4] = {};
#pragma unroll
    for (int js = 0; js < 128; js += 32) {
      bf16x8 av = *(const bf16x8*)&vt_s[(w * 16 + l16) * 136 + q * 8 + js];
      bf16x8 bk3[4];
#pragma unroll
      for (int kt = 0; kt < 4; kt++)
        bk3[kt] = *(const bf16x8*)&kwt_s[(kt * 16 + l16) * 136 + q * 8 + js];
#pragma unroll
      for (int kt = 0; kt < 4; kt++)
        accZ[kt] = __builtin_amdgcn_mfma_f32_16x16x32_bf16(av, bk3[kt], accZ[kt], 0, 0, 0);
    }
    // accB = rr @ Z_old   (wave owns i-rows w*32..w*32+31)
    floatx4 accB[2][4] = {};
    int i0 = w * 32;
#pragma unroll
    for (int ks = 0; ks < 64; ks += 32) {
      bf16x8 af2[2], bz[4];
#pragma unroll
      for (int it2 = 0; it2 < 2; it2++)
        af2[it2] = *(const bf16x8*)&rr_s[(i0 + it2 * 16 + l16) * 72 + q * 8 + ks];
#pragma unroll
      for (int vt2 = 0; vt2 < 4; vt2++) {
        const float* zp = &z_s[(vt2 * 16 + l16) * 68 + ks + q * 8];
        bf16x8 t;
#pragma unroll
        for (int e2 = 0; e2 < 8; e2++) t[e2] = (__bf16)zp[e2];
        bz[vt2] = t;
      }
#pragma unroll
      for (int it2 = 0; it2 < 2; it2++)
#pragma unroll
        for (int vt2 = 0; vt2 < 4; vt2++)
          accB[it2][vt2] = __builtin_amdgcn_mfma_f32_16x16x32_bf16(
              af2[it2], bz[vt2], accB[it2][vt2], 0, 0, 0);
    }
    __syncthreads();

    // ---------- phase 2 ----------
    // state update: Z = ws*Z + accZ   (wave owns its 16 v-rows)
#pragma unroll
    for (int kt = 0; kt < 4; kt++)
#pragma unroll
      for (int rg = 0; rg < 4; rg++) {
        int zi = (w * 16 + q * 4 + rg) * 68 + kt * 16 + l16;
        z_s[zi] = wsf * z_s[zi] + accZ[kt][rg];
      }
    // accO = P @ vv
    floatx4 accO[2][4] = {};
#pragma unroll
    for (int js = 0; js < 128; js += 32) {
      bf16x8 af3[2], bv[4];
#pragma unroll
      for (int it2 = 0; it2 < 2; it2++)
        af3[it2] = *(const bf16x8*)&p_s[(i0 + it2 * 16 + l16) * 136 + q * 8 + js];
#pragma unroll
      for (int vt2 = 0; vt2 < 4; vt2++)
        bv[vt2] = *(const bf16x8*)&vt_s[(vt2 * 16 + l16) * 136 + q * 8 + js];
#pragma unroll
      for (int it2 = 0; it2 < 2; it2++)
#pragma unroll
        for (int vt2 = 0; vt2 < 4; vt2++)
          accO[it2][vt2] = __builtin_amdgcn_mfma_f32_16x16x32_bf16(
              af3[it2], bv[vt2], accO[it2][vt2], 0, 0, 0);
    }
    // epilogue: out = accO + wb[i]*accB; GroupNorm over 64 ch; *lnw+lnb; *g
#pragma unroll
    for (int it2 = 0; it2 < 2; it2++)
#pragma unroll
      for (int rg = 0; rg < 4; rg++) {
        int i = i0 + it2 * 16 + q * 4 + rg;
        float wbi = expf(-(float)i * etd);  // decay^i
        float vals[4];
        float s1 = 0.f, s2 = 0.f;
#pragma unroll
        for (int vt2 = 0; vt2 < 4; vt2++) {
          float val = accO[it2][vt2][rg] + wbi * accB[it2][vt2][rg];
          vals[vt2] = val; s1 += val; s2 += val * val;
        }
#pragma unroll
        for (int mm = 1; mm < 16; mm <<= 1) {
          s1 += __shfl_xor(s1, mm, 64);
          s2 += __shfl_xor(s2, mm, 64);
        }
        float mu = s1 * (1.f / 64.f);
        float va = s2 * (1.f / 64.f) - mu * mu;
        float rinv = rsqrtf(va + 64.f * 1e-5f);  // folds /8 + eps
        long rowg = (long)b * TT_DIM + n * T_CH + i;
#pragma unroll
        for (int vt2 = 0; vt2 < 4; vt2++) {
          int c = h * K_DIM + vt2 * 16 + l16;
          float y = (vals[vt2] - mu) * rinv * lnw[c] + lnb[c];
          float gf = bf2f(gBuf[rowg * C_DIM + c]);
          gy[rowg * C_DIM + c] = f2bf(y * gf);
        }
      }
  }
}

// ============================================================
extern "C" void kernel_launch(void* const* d_in, const int* in_sizes, int n_in,
                              void* d_out, int out_size, void* d_ws,
                              size_t ws_size, hipStream_t stream) {
  const float* xq  = (const float*)d_in[0];
  const float* tmk = (const float*)d_in[1];
  const float* tmv = (const float*)d_in[2];
  const float* tmr = (const float*)d_in[3];
  const float* tmg = (const float*)d_in[4];
  const float* td  = (const float*)d_in[5];
  const float* tf  = (const float*)d_in[6];
  const float* Wr  = (const float*)d_in[7];
  const float* Wk  = (const float*)d_in[8];
  const float* Wv  = (const float*)d_in[9];
  const float* Wg  = (const float*)d_in[10];
  const float* Wo  = (const float*)d_in[11];
  const float* lnw = (const float*)d_in[12];
  const float* lnb = (const float*)d_in[13];

  char* ws = (char*)d_ws;
  const size_t BUF = (size_t)M_ROWS * C_DIM * 2;  // 32 MiB bf16 buffer
  ushort* b0 = (ushort*)(ws + 0 * BUF);  // xr -> later k
  ushort* b1 = (ushort*)(ws + 1 * BUF);  // xk -> later v
  ushort* b2 = (ushort*)(ws + 2 * BUF);  // xv -> later g(silu)
  ushort* b3 = (ushort*)(ws + 3 * BUF);  // xg -> later gy
  ushort* b4 = (ushort*)(ws + 4 * BUF);  // r
  ushort* wcv = (ushort*)(ws + 5 * BUF); // 5x 1M bf16 weights
  const ushort* wr_b = wcv;
  const ushort* wk_b = wcv + (1 << 20);
  const ushort* wv_b = wcv + 2 * (1 << 20);
  const ushort* wg_b = wcv + 3 * (1 << 20);
  const ushort* wo_b = wcv + 4 * (1 << 20);

  mix_kernel<<<16384, 256, 0, stream>>>(xq, tmk, tmv, tmr, tmg, b0, b1, b2, b3);
  wconv_kernel<<<5120, 256, 0, stream>>>(Wr, Wk, Wv, Wg, Wo, wcv);

  dim3 gg(8, 128);
  gemm_bt<0><<<gg, 256, 0, stream>>>(b0, wr_b, b4);  // r
  gemm_bt<0><<<gg, 256, 0, stream>>>(b1, wk_b, b0);  // k
  gemm_bt<0><<<gg, 256, 0, stream>>>(b2, wv_b, b1);  // v
  gemm_bt<1><<<gg, 256, 0, stream>>>(b3, wg_b, b2);  // g = silu(xg@Wg^T)

  rwkv_attn<<<64, 256, 0, stream>>>(b4, b0, b1, b2, td, tf, lnw, lnb, b3);

  gemm_bt<2><<<gg, 256, 0, stream>>>(b3, wo_b, (float*)d_out);  // fp32 out
}

// Round 2
// 543.079 us; speedup vs baseline: 1.5637x; 1.5637x over previous
//
#include <hip/hip_runtime.h>
#include <hip/hip_bf16.h>
#include <stdint.h>

// ---- problem constants ----
#define C_DIM 1024
#define H_DIM 16
#define K_DIM 64
#define T_CH 128
#define TT_DIM 4096
#define B_DIM 4
#define N_CH 32
#define M_ROWS 16384  // B*TT

typedef __attribute__((ext_vector_type(8))) __bf16 bf16x8;
typedef __attribute__((ext_vector_type(4))) float floatx4;

__device__ __forceinline__ float bf2f(ushort u) {
  union { uint32_t i; float f; } v; v.i = ((uint32_t)u) << 16; return v.f;
}
__device__ __forceinline__ ushort f2bf(float f) {
  union { float f; uint32_t i; } v; v.f = f;
  return (ushort)((v.i + 0x7fffu + ((v.i >> 16) & 1u)) >> 16);  // RNE
}

#define GLOAD_LDS16(g, l)                                                     \
  __builtin_amdgcn_global_load_lds(                                           \
      (const __attribute__((address_space(1))) void*)(g),                     \
      (__attribute__((address_space(3))) void*)(l), 16, 0, 0)

// ============================================================
// 1) time-shift mix: xr/xk/xv/xg (bf16) from x (fp32)
// ============================================================
__global__ __launch_bounds__(256) void mix_kernel(
    const float* __restrict__ x,
    const float* __restrict__ mk, const float* __restrict__ mv,
    const float* __restrict__ mr, const float* __restrict__ mg,
    ushort* __restrict__ xr, ushort* __restrict__ xk,
    ushort* __restrict__ xv, ushort* __restrict__ xg) {
  long idx = (long)blockIdx.x * 256 + threadIdx.x;
  long e = idx * 4;
  int c = (int)(e & (C_DIM - 1));
  long row = e >> 10;
  int t = (int)(row & (TT_DIM - 1));
  floatx4 xc = *(const floatx4*)(x + e);
  floatx4 xp = {0.f, 0.f, 0.f, 0.f};
  if (t != 0) xp = *(const floatx4*)(x + e - C_DIM);
  floatx4 d = xc - xp;
  floatx4 vk = *(const floatx4*)(mk + c);
  floatx4 vv = *(const floatx4*)(mv + c);
  floatx4 vr = *(const floatx4*)(mr + c);
  floatx4 vg = *(const floatx4*)(mg + c);
  floatx4 ok = xp + d * vk;
  floatx4 ov = xp + d * vv;
  floatx4 orr = xp + d * vr;
  floatx4 og = xp + d * vg;
  union { ushort u[4]; uint2 q; } pk;
#define ST(dst, val)                                                          \
  pk.u[0] = f2bf(val.x); pk.u[1] = f2bf(val.y);                               \
  pk.u[2] = f2bf(val.z); pk.u[3] = f2bf(val.w);                               \
  *(uint2*)((dst) + e) = pk.q;
  ST(xk, ok) ST(xv, ov) ST(xr, orr) ST(xg, og)
#undef ST
}

// ============================================================
// 2) fp32 -> bf16 weight conversion (5 weights concatenated)
// ============================================================
__global__ __launch_bounds__(256) void wconv_kernel(
    const float* __restrict__ w0, const float* __restrict__ w1,
    const float* __restrict__ w2, const float* __restrict__ w3,
    const float* __restrict__ w4, ushort* __restrict__ o) {
  long idx = (long)blockIdx.x * 256 + threadIdx.x;
  long e = idx * 4;
  int wi = (int)(e >> 20);
  long off = e & ((1L << 20) - 1);
  const float* src = wi == 0 ? w0 : wi == 1 ? w1 : wi == 2 ? w2 : wi == 3 ? w3 : w4;
  floatx4 vv = *(const floatx4*)(src + off);
  union { ushort u[4]; uint2 q; } pk;
  pk.u[0] = f2bf(vv.x); pk.u[1] = f2bf(vv.y);
  pk.u[2] = f2bf(vv.z); pk.u[3] = f2bf(vv.w);
  *(uint2*)(o + e) = pk.q;
}

// ============================================================
// 3) bf16 GEMM: C[M,N] = A[M,K] * Bt[N,K]^T  (m97 structure)
//    M=16384, N=K=1024 fixed. EPI: 0=bf16, 1=bf16+silu, 2=fp32
// ============================================================
template <int EPI>
__global__ __launch_bounds__(256) void gemm_bt(
    const ushort* __restrict__ A, const ushort* __restrict__ Bt,
    void* __restrict__ Cout) {
  __shared__ __align__(16) ushort As[128 * 32];
  __shared__ __align__(16) ushort Bs[128 * 32];
  int tid = threadIdx.x;
  int lane = tid & 63, w = tid >> 6;
  int q = lane >> 4, l16 = lane & 15;
  int wm = w >> 1, wn = w & 1;
  int bn = blockIdx.x, bm = blockIdx.y;

  const ushort* gA0 = A + (long)(bm * 128 + w * 16 + (lane >> 2)) * C_DIM + (lane & 3) * 8;
  const ushort* gA1 = gA0 + 64 * C_DIM;
  const ushort* gB0 = Bt + (long)(bn * 128 + w * 16 + (lane >> 2)) * C_DIM + (lane & 3) * 8;
  const ushort* gB1 = gB0 + 64 * C_DIM;
  ushort* lA0 = As + (w * 16) * 32;
  ushort* lA1 = As + (64 + w * 16) * 32;
  ushort* lB0 = Bs + (w * 16) * 32;
  ushort* lB1 = Bs + (64 + w * 16) * 32;

  floatx4 acc[4][4] = {};

  for (int k0 = 0; k0 < C_DIM; k0 += 32) {
    __syncthreads();
    GLOAD_LDS16(gA0, lA0);
    GLOAD_LDS16(gA1, lA1);
    GLOAD_LDS16(gB0, lB0);
    GLOAD_LDS16(gB1, lB1);
    gA0 += 32; gA1 += 32; gB0 += 32; gB1 += 32;
    __syncthreads();
    bf16x8 af[4], bfv[4];
#pragma unroll
    for (int i = 0; i < 4; i++)
      af[i] = *(const bf16x8*)&As[(wm * 64 + i * 16 + l16) * 32 + q * 8];
#pragma unroll
    for (int i = 0; i < 4; i++)
      bfv[i] = *(const bf16x8*)&Bs[(wn * 64 + i * 16 + l16) * 32 + q * 8];
#pragma unroll
    for (int mi = 0; mi < 4; mi++)
#pragma unroll
      for (int ni = 0; ni < 4; ni++)
        acc[mi][ni] = __builtin_amdgcn_mfma_f32_16x16x32_bf16(
            af[mi], bfv[ni], acc[mi][ni], 0, 0, 0);
  }

  int row0 = bm * 128 + wm * 64 + q * 4;
  int col0 = bn * 128 + wn * 64 + l16;
#pragma unroll
  for (int mi = 0; mi < 4; mi++)
#pragma unroll
    for (int ni = 0; ni < 4; ni++)
#pragma unroll
      for (int rg = 0; rg < 4; rg++) {
        long off = (long)(row0 + mi * 16 + rg) * C_DIM + col0 + ni * 16;
        float val = acc[mi][ni][rg];
        if (EPI == 1) val = val / (1.f + expf(-val));  // silu
        if (EPI == 2)
          ((float*)Cout)[off] = val;
        else
          ((ushort*)Cout)[off] = f2bf(val);
      }
}

// ============================================================
// 4a) per-chunk state contribution: Zc[bh][n][v][k] (bf16)
//     Zc = vv^T @ (kk * wk),  wk[j] = decay^(T-1-j)
//     grid = 2048 blocks (bh*32 + n)
// ============================================================
__global__ __launch_bounds__(256) void chunk_state(
    const ushort* __restrict__ kB, const ushort* __restrict__ vB,
    const float* __restrict__ td, ushort* __restrict__ Zc) {
  __shared__ __align__(16) ushort vt_s[64 * 136];   // vv^T  [v][j]
  __shared__ __align__(16) ushort kwt_s[64 * 136];  // (kk*wk)^T [k][j]
  int blk = blockIdx.x;
  int bh = blk >> 5, n = blk & 31;
  int b = bh >> 4, h = bh & 15;
  int tid = threadIdx.x;
  int lane = tid & 63, w = tid >> 6;
  int q = lane >> 4, l16 = lane & 15;
  float etd = expf(td[h]);
  long cbase = ((long)b * TT_DIM + n * T_CH) * C_DIM + h * K_DIM;

#pragma unroll
  for (int it = 0; it < 4; it++) {
    int chunk = it * 256 + tid;
    int row = chunk >> 3;
    int cc = (chunk & 7) * 8;
    long ga = cbase + (long)row * C_DIM + cc;
    uint4 kv4 = *(const uint4*)(kB + ga);
    uint4 vv4 = *(const uint4*)(vB + ga);
    float wkj = expf(-(float)(T_CH - 1 - row) * etd);
    const ushort* kp = (const ushort*)&kv4;
    const ushort* vp = (const ushort*)&vv4;
#pragma unroll
    for (int e2 = 0; e2 < 8; e2++) {
      kwt_s[(cc + e2) * 136 + row] = f2bf(bf2f(kp[e2]) * wkj);
      vt_s[(cc + e2) * 136 + row] = vp[e2];
    }
  }
  __syncthreads();

  floatx4 accZ[4] = {};
#pragma unroll
  for (int js = 0; js < 128; js += 32) {
    bf16x8 av = *(const bf16x8*)&vt_s[(w * 16 + l16) * 136 + q * 8 + js];
    bf16x8 bk3[4];
#pragma unroll
    for (int kt = 0; kt < 4; kt++)
      bk3[kt] = *(const bf16x8*)&kwt_s[(kt * 16 + l16) * 136 + q * 8 + js];
#pragma unroll
    for (int kt = 0; kt < 4; kt++)
      accZ[kt] = __builtin_amdgcn_mfma_f32_16x16x32_bf16(av, bk3[kt], accZ[kt], 0, 0, 0);
  }
  long zbase = (long)blk * 4096;
#pragma unroll
  for (int kt = 0; kt < 4; kt++)
#pragma unroll
    for (int rg = 0; rg < 4; rg++)
      Zc[zbase + (w * 16 + q * 4 + rg) * 64 + kt * 16 + l16] = f2bf(accZ[kt][rg]);
}

// ============================================================
// 4b) state scan over chunks: Sb[bh][n] = state BEFORE chunk n
//     S_{n+1} = ws * S_n + Zc_n ; element-parallel (262144 scans)
// ============================================================
__global__ __launch_bounds__(256) void state_scan(
    const ushort* __restrict__ Zc, const float* __restrict__ td,
    ushort* __restrict__ Sb) {
  long tg = (long)blockIdx.x * 256 + threadIdx.x;  // 0..262143
  int bh = (int)(tg >> 12);
  int e = (int)(tg & 4095);
  int h = bh & 15;
  float wsf = expf(-128.f * expf(td[h]));  // decay^T
  float s = 0.f;
  long base = (long)bh * N_CH * 4096 + e;
#pragma unroll
  for (int n = 0; n < N_CH; n++) {
    Sb[base + n * 4096] = f2bf(s);
    s = wsf * s + bf2f(Zc[base + n * 4096]);
  }
}

// ============================================================
// 4c) per-chunk output + GroupNorm + *g -> gy (bf16)
//     grid = 2048 blocks (bh*32 + n); kk/P share one LDS buffer
// ============================================================
__global__ __launch_bounds__(256) void chunk_out(
    const ushort* __restrict__ rB, const ushort* __restrict__ kB,
    const ushort* __restrict__ vB, const ushort* __restrict__ gBuf,
    const ushort* __restrict__ Sb,
    const float* __restrict__ td, const float* __restrict__ tf,
    const float* __restrict__ lnw, const float* __restrict__ lnb,
    ushort* __restrict__ gy) {
  __shared__ __align__(16) ushort rr_s[128 * 72];   // rr row-major
  __shared__ __align__(16) ushort un_s[128 * 136];  // kk (phase1) then P
  __shared__ __align__(16) ushort vt_s[64 * 136];   // vv^T [v][j]
  __shared__ __align__(16) ushort z_s[64 * 72];     // state Z=S^T bf16 [v][k]

  int blk = blockIdx.x;
  int bh = blk >> 5, n = blk & 31;
  int b = bh >> 4, h = bh & 15;
  int tid = threadIdx.x;
  int lane = tid & 63, w = tid >> 6;
  int q = lane >> 4, l16 = lane & 15;

  float etd = expf(td[h]);
  float u = tf[h];
  long cbase = ((long)b * TT_DIM + n * T_CH) * C_DIM + h * K_DIM;

  // stage rr / kk / vv^T
#pragma unroll
  for (int it = 0; it < 4; it++) {
    int chunk = it * 256 + tid;
    int row = chunk >> 3;
    int cc = (chunk & 7) * 8;
    long ga = cbase + (long)row * C_DIM + cc;
    *(uint4*)&rr_s[row * 72 + cc] = *(const uint4*)(rB + ga);
    *(uint4*)&un_s[row * 136 + cc] = *(const uint4*)(kB + ga);
    uint4 vv4 = *(const uint4*)(vB + ga);
    const ushort* vp = (const ushort*)&vv4;
#pragma unroll
    for (int e2 = 0; e2 < 8; e2++) vt_s[(cc + e2) * 136 + row] = vp[e2];
  }
  // stage state (64x64 bf16)
  {
    long sbase = (long)blk * 4096;
    int v = tid >> 2, c0 = (tid & 3) * 16;
    *(uint4*)&z_s[v * 72 + c0] = *(const uint4*)(Sb + sbase + v * 64 + c0);
    *(uint4*)&z_s[v * 72 + c0 + 8] = *(const uint4*)(Sb + sbase + v * 64 + c0 + 8);
  }
  __syncthreads();

  // ---- phase 1: att = rr @ kk^T (wave quadrant) ----
  floatx4 accA[4][4] = {};
  int ai0 = (w >> 1) * 64, aj0 = (w & 1) * 64;
#pragma unroll
  for (int ks = 0; ks < 64; ks += 32) {
    bf16x8 af[4], bk2[4];
#pragma unroll
    for (int i = 0; i < 4; i++)
      af[i] = *(const bf16x8*)&rr_s[(ai0 + i * 16 + l16) * 72 + q * 8 + ks];
#pragma unroll
    for (int j = 0; j < 4; j++)
      bk2[j] = *(const bf16x8*)&un_s[(aj0 + j * 16 + l16) * 136 + q * 8 + ks];
#pragma unroll
    for (int mi = 0; mi < 4; mi++)
#pragma unroll
      for (int nj = 0; nj < 4; nj++)
        accA[mi][nj] = __builtin_amdgcn_mfma_f32_16x16x32_bf16(
            af[mi], bk2[nj], accA[mi][nj], 0, 0, 0);
  }

  // accB = rr @ S   (wave owns i-rows w*32..w*32+31)
  floatx4 accB[2][4] = {};
  int i0 = w * 32;
#pragma unroll
  for (int ks = 0; ks < 64; ks += 32) {
    bf16x8 af2[2], bz[4];
#pragma unroll
    for (int it2 = 0; it2 < 2; it2++)
      af2[it2] = *(const bf16x8*)&rr_s[(i0 + it2 * 16 + l16) * 72 + q * 8 + ks];
#pragma unroll
    for (int vt2 = 0; vt2 < 4; vt2++)
      bz[vt2] = *(const bf16x8*)&z_s[(vt2 * 16 + l16) * 72 + q * 8 + ks];
#pragma unroll
    for (int it2 = 0; it2 < 2; it2++)
#pragma unroll
      for (int vt2 = 0; vt2 < 4; vt2++)
        accB[it2][vt2] = __builtin_amdgcn_mfma_f32_16x16x32_bf16(
            af2[it2], bz[vt2], accB[it2][vt2], 0, 0, 0);
  }
  __syncthreads();  // kk reads complete everywhere

  // write P = att * w_mat into union buffer (overwrites kk)
#pragma unroll
  for (int mi = 0; mi < 4; mi++)
#pragma unroll
    for (int nj = 0; nj < 4; nj++)
#pragma unroll
      for (int rg = 0; rg < 4; rg++) {
        int i = ai0 + mi * 16 + q * 4 + rg;
        int j = aj0 + nj * 16 + l16;
        float wv = 0.f;
        if (i > j) wv = expf(-(float)(i - j - 1) * etd);
        else if (i == j) wv = u;
        un_s[i * 136 + j] = f2bf(accA[mi][nj][rg] * wv);
      }
  __syncthreads();

  // ---- phase 2: accO = P @ vv ----
  floatx4 accO[2][4] = {};
#pragma unroll
  for (int js = 0; js < 128; js += 32) {
    bf16x8 af3[2], bv[4];
#pragma unroll
    for (int it2 = 0; it2 < 2; it2++)
      af3[it2] = *(const bf16x8*)&un_s[(i0 + it2 * 16 + l16) * 136 + q * 8 + js];
#pragma unroll
    for (int vt2 = 0; vt2 < 4; vt2++)
      bv[vt2] = *(const bf16x8*)&vt_s[(vt2 * 16 + l16) * 136 + q * 8 + js];
#pragma unroll
    for (int it2 = 0; it2 < 2; it2++)
#pragma unroll
      for (int vt2 = 0; vt2 < 4; vt2++)
        accO[it2][vt2] = __builtin_amdgcn_mfma_f32_16x16x32_bf16(
            af3[it2], bv[vt2], accO[it2][vt2], 0, 0, 0);
  }

  // epilogue: out = accO + wb[i]*accB; GroupNorm; *lnw+lnb; *g
#pragma unroll
  for (int it2 = 0; it2 < 2; it2++)
#pragma unroll
    for (int rg = 0; rg < 4; rg++) {
      int i = i0 + it2 * 16 + q * 4 + rg;
      float wbi = expf(-(float)i * etd);  // decay^i
      float vals[4];
      float s1 = 0.f, s2 = 0.f;
#pragma unroll
      for (int vt2 = 0; vt2 < 4; vt2++) {
        float val = accO[it2][vt2][rg] + wbi * accB[it2][vt2][rg];
        vals[vt2] = val; s1 += val; s2 += val * val;
      }
#pragma unroll
      for (int mm = 1; mm < 16; mm <<= 1) {
        s1 += __shfl_xor(s1, mm, 64);
        s2 += __shfl_xor(s2, mm, 64);
      }
      float mu = s1 * (1.f / 64.f);
      float va = s2 * (1.f / 64.f) - mu * mu;
      float rinv = rsqrtf(va + 64.f * 1e-5f);  // folds /8 + eps
      long rowg = (long)b * TT_DIM + n * T_CH + i;
#pragma unroll
      for (int vt2 = 0; vt2 < 4; vt2++) {
        int c = h * K_DIM + vt2 * 16 + l16;
        float y = (vals[vt2] - mu) * rinv * lnw[c] + lnb[c];
        float gf = bf2f(gBuf[rowg * C_DIM + c]);
        gy[rowg * C_DIM + c] = f2bf(y * gf);
      }
    }
}

// ============================================================
extern "C" void kernel_launch(void* const* d_in, const int* in_sizes, int n_in,
                              void* d_out, int out_size, void* d_ws,
                              size_t ws_size, hipStream_t stream) {
  const float* xq  = (const float*)d_in[0];
  const float* tmk = (const float*)d_in[1];
  const float* tmv = (const float*)d_in[2];
  const float* tmr = (const float*)d_in[3];
  const float* tmg = (const float*)d_in[4];
  const float* td  = (const float*)d_in[5];
  const float* tf  = (const float*)d_in[6];
  const float* Wr  = (const float*)d_in[7];
  const float* Wk  = (const float*)d_in[8];
  const float* Wv  = (const float*)d_in[9];
  const float* Wg  = (const float*)d_in[10];
  const float* Wo  = (const float*)d_in[11];
  const float* lnw = (const float*)d_in[12];
  const float* lnb = (const float*)d_in[13];

  char* ws = (char*)d_ws;
  const size_t BUF = (size_t)M_ROWS * C_DIM * 2;  // 32 MiB bf16 buffer
  ushort* b0 = (ushort*)(ws + 0 * BUF);  // xr -> later k
  ushort* b1 = (ushort*)(ws + 1 * BUF);  // xk -> later v
  ushort* b2 = (ushort*)(ws + 2 * BUF);  // xv -> later g(silu)
  ushort* b3 = (ushort*)(ws + 3 * BUF);  // xg -> later gy
  ushort* wcv = (ushort*)(ws + 4 * BUF); // 5x 1M bf16 weights (10 MiB)
  const ushort* wr_b = wcv;
  const ushort* wk_b = wcv + (1 << 20);
  const ushort* wv_b = wcv + 2 * (1 << 20);
  const ushort* wg_b = wcv + 3 * (1 << 20);
  const ushort* wo_b = wcv + 4 * (1 << 20);
  ushort* Zc = (ushort*)(ws + 4 * BUF + 5 * (2 << 20));           // 16 MiB
  ushort* Sb = Zc + (size_t)64 * N_CH * 4096;                     // 16 MiB
  ushort* rbuf = (ushort*)d_out;  // bf16 r parked in d_out scratch (32 MiB)

  mix_kernel<<<16384, 256, 0, stream>>>(xq, tmk, tmv, tmr, tmg, b0, b1, b2, b3);
  wconv_kernel<<<5120, 256, 0, stream>>>(Wr, Wk, Wv, Wg, Wo, wcv);

  dim3 gg(8, 128);
  gemm_bt<0><<<gg, 256, 0, stream>>>(b0, wr_b, rbuf);  // r
  gemm_bt<0><<<gg, 256, 0, stream>>>(b1, wk_b, b0);    // k
  gemm_bt<0><<<gg, 256, 0, stream>>>(b2, wv_b, b1);    // v
  gemm_bt<1><<<gg, 256, 0, stream>>>(b3, wg_b, b2);    // g = silu(xg@Wg^T)

  chunk_state<<<2048, 256, 0, stream>>>(b0, b1, td, Zc);
  state_scan<<<1024, 256, 0, stream>>>(Zc, td, Sb);
  chunk_out<<<2048, 256, 0, stream>>>(rbuf, b0, b1, b2, Sb, td, tf, lnw, lnb, b3);

  gemm_bt<2><<<gg, 256, 0, stream>>>(b3, wo_b, (float*)d_out);  // fp32 out
}

// Round 5
// 486.012 us; speedup vs baseline: 1.7473x; 1.1174x over previous
//
#include <hip/hip_runtime.h>
#include <hip/hip_bf16.h>
#include <stdint.h>

// ---- problem constants ----
#define C_DIM 1024
#define H_DIM 16
#define K_DIM 64
#define T_CH 128
#define TT_DIM 4096
#define B_DIM 4
#define N_CH 32
#define M_ROWS 16384  // B*TT

typedef __attribute__((ext_vector_type(8))) __bf16 bf16x8;
typedef __attribute__((ext_vector_type(4))) float floatx4;

__device__ __forceinline__ float bf2f(ushort u) {
  union { uint32_t i; float f; } v; v.i = ((uint32_t)u) << 16; return v.f;
}
__device__ __forceinline__ ushort f2bf(float f) {
  union { float f; uint32_t i; } v; v.f = f;
  return (ushort)((v.i + 0x7fffu + ((v.i >> 16) & 1u)) >> 16);  // RNE
}

#define GLOAD_LDS16(g, l)                                                     \
  __builtin_amdgcn_global_load_lds(                                           \
      (const __attribute__((address_space(1))) void*)(g),                     \
      (__attribute__((address_space(3))) void*)(l), 16, 0, 0)

// ============================================================
// 1) time-shift mix: xr/xk/xv/xg (bf16) from x (fp32)   [round-2 numerics]
// ============================================================
__global__ __launch_bounds__(256) void mix_kernel(
    const float* __restrict__ x,
    const float* __restrict__ mk, const float* __restrict__ mv,
    const float* __restrict__ mr, const float* __restrict__ mg,
    ushort* __restrict__ xr, ushort* __restrict__ xk,
    ushort* __restrict__ xv, ushort* __restrict__ xg) {
  long idx = (long)blockIdx.x * 256 + threadIdx.x;
  long e = idx * 4;
  int c = (int)(e & (C_DIM - 1));
  long row = e >> 10;
  int t = (int)(row & (TT_DIM - 1));
  floatx4 xc = *(const floatx4*)(x + e);
  floatx4 xp = {0.f, 0.f, 0.f, 0.f};
  if (t != 0) xp = *(const floatx4*)(x + e - C_DIM);
  floatx4 d = xc - xp;
  floatx4 vk = *(const floatx4*)(mk + c);
  floatx4 vv = *(const floatx4*)(mv + c);
  floatx4 vr = *(const floatx4*)(mr + c);
  floatx4 vg = *(const floatx4*)(mg + c);
  floatx4 ok = xp + d * vk;
  floatx4 ov = xp + d * vv;
  floatx4 orr = xp + d * vr;
  floatx4 og = xp + d * vg;
  union { ushort u[4]; uint2 q; } pk;
#define ST(dst, val)                                                          \
  pk.u[0] = f2bf(val.x); pk.u[1] = f2bf(val.y);                               \
  pk.u[2] = f2bf(val.z); pk.u[3] = f2bf(val.w);                               \
  *(uint2*)((dst) + e) = pk.q;
  ST(xk, ok) ST(xv, ov) ST(xr, orr) ST(xg, og)
#undef ST
}

// ============================================================
// 2) fp32 -> bf16 weight conversion (5 weights concatenated)
// ============================================================
__global__ __launch_bounds__(256) void wconv_kernel(
    const float* __restrict__ w0, const float* __restrict__ w1,
    const float* __restrict__ w2, const float* __restrict__ w3,
    const float* __restrict__ w4, ushort* __restrict__ o) {
  long idx = (long)blockIdx.x * 256 + threadIdx.x;
  long e = idx * 4;
  int wi = (int)(e >> 20);
  long off = e & ((1L << 20) - 1);
  const float* src = wi == 0 ? w0 : wi == 1 ? w1 : wi == 2 ? w2 : wi == 3 ? w3 : w4;
  floatx4 vv = *(const floatx4*)(src + off);
  union { ushort u[4]; uint2 q; } pk;
  pk.u[0] = f2bf(vv.x); pk.u[1] = f2bf(vv.y);
  pk.u[2] = f2bf(vv.z); pk.u[3] = f2bf(vv.w);
  *(uint2*)(o + e) = pk.q;
}

// ============================================================
// 3) bf16 GEMM: C[M,N] = A[M,K] * Bt[N,K]^T  (m97 structure)
//    M=16384, N=K=1024. EPI: 0=bf16, 1=bf16+silu, 2=fp32.
//    1D grid of 1024 blocks, XCD-swizzled so that the 8 bn-blocks
//    sharing an A row-tile land on ONE XCD (id%8 == bm%8):
//      bn = (id>>3)&7 ; bm = (id&7) | ((id>>6)<<3)
//    K-loop unrolled 2x (BK=64, two 32-col LDS panels, 1 barrier pair
//    per 64 K) — math order identical to BK=32 loop.
// ============================================================
template <int EPI>
__global__ __launch_bounds__(256) void gemm_bt(
    const ushort* __restrict__ A, const ushort* __restrict__ Bt,
    void* __restrict__ Cout) {
  __shared__ __align__(16) ushort As[2][128 * 32];
  __shared__ __align__(16) ushort Bs[2][128 * 32];
  int tid = threadIdx.x;
  int lane = tid & 63, w = tid >> 6;
  int q = lane >> 4, l16 = lane & 15;
  int wm = w >> 1, wn = w & 1;
  int id = blockIdx.x;
  int bn = (id >> 3) & 7;
  int bm = (id & 7) | ((id >> 6) << 3);

  const ushort* gA0 = A + (long)(bm * 128 + w * 16 + (lane >> 2)) * C_DIM + (lane & 3) * 8;
  const ushort* gA1 = gA0 + 64 * C_DIM;
  const ushort* gB0 = Bt + (long)(bn * 128 + w * 16 + (lane >> 2)) * C_DIM + (lane & 3) * 8;
  const ushort* gB1 = gB0 + 64 * C_DIM;
  // wave-uniform LDS bases (hw adds lane*16B)
  ushort* lA0 = As[0] + (w * 16) * 32;
  ushort* lA1 = As[0] + (64 + w * 16) * 32;
  ushort* lB0 = Bs[0] + (w * 16) * 32;
  ushort* lB1 = Bs[0] + (64 + w * 16) * 32;
  ushort* lA0p = As[1] + (w * 16) * 32;
  ushort* lA1p = As[1] + (64 + w * 16) * 32;
  ushort* lB0p = Bs[1] + (w * 16) * 32;
  ushort* lB1p = Bs[1] + (64 + w * 16) * 32;

  floatx4 acc[4][4] = {};

  for (int k0 = 0; k0 < C_DIM; k0 += 64) {
    __syncthreads();
    GLOAD_LDS16(gA0, lA0);
    GLOAD_LDS16(gA1, lA1);
    GLOAD_LDS16(gB0, lB0);
    GLOAD_LDS16(gB1, lB1);
    GLOAD_LDS16(gA0 + 32, lA0p);
    GLOAD_LDS16(gA1 + 32, lA1p);
    GLOAD_LDS16(gB0 + 32, lB0p);
    GLOAD_LDS16(gB1 + 32, lB1p);
    gA0 += 64; gA1 += 64; gB0 += 64; gB1 += 64;
    __syncthreads();
#pragma unroll
    for (int p = 0; p < 2; p++) {
      bf16x8 af[4], bfv[4];
#pragma unroll
      for (int i = 0; i < 4; i++)
        af[i] = *(const bf16x8*)&As[p][(wm * 64 + i * 16 + l16) * 32 + q * 8];
#pragma unroll
      for (int i = 0; i < 4; i++)
        bfv[i] = *(const bf16x8*)&Bs[p][(wn * 64 + i * 16 + l16) * 32 + q * 8];
#pragma unroll
      for (int mi = 0; mi < 4; mi++)
#pragma unroll
        for (int ni = 0; ni < 4; ni++)
          acc[mi][ni] = __builtin_amdgcn_mfma_f32_16x16x32_bf16(
              af[mi], bfv[ni], acc[mi][ni], 0, 0, 0);
    }
  }

  int row0 = bm * 128 + wm * 64 + q * 4;
  int col0 = bn * 128 + wn * 64 + l16;
#pragma unroll
  for (int mi = 0; mi < 4; mi++)
#pragma unroll
    for (int ni = 0; ni < 4; ni++)
#pragma unroll
      for (int rg = 0; rg < 4; rg++) {
        long off = (long)(row0 + mi * 16 + rg) * C_DIM + col0 + ni * 16;
        float val = acc[mi][ni][rg];
        if (EPI == 1) val = val / (1.f + expf(-val));  // silu
        if (EPI == 2)
          ((float*)Cout)[off] = val;
        else
          ((ushort*)Cout)[off] = f2bf(val);
      }
}

// ============================================================
// 4a) per-chunk state contribution: Zc = vv^T @ (kk*wk)   (bf16)
// ============================================================
__global__ __launch_bounds__(256) void chunk_state(
    const ushort* __restrict__ kB, const ushort* __restrict__ vB,
    const float* __restrict__ td, ushort* __restrict__ Zc) {
  __shared__ __align__(16) ushort vt_s[64 * 136];
  __shared__ __align__(16) ushort kwt_s[64 * 136];
  int blk = blockIdx.x;
  int bh = blk >> 5, n = blk & 31;
  int b = bh >> 4, h = bh & 15;
  int tid = threadIdx.x;
  int lane = tid & 63, w = tid >> 6;
  int q = lane >> 4, l16 = lane & 15;
  float etd = expf(td[h]);
  long cbase = ((long)b * TT_DIM + n * T_CH) * C_DIM + h * K_DIM;

#pragma unroll
  for (int it = 0; it < 4; it++) {
    int chunk = it * 256 + tid;
    int row = chunk >> 3;
    int cc = (chunk & 7) * 8;
    long ga = cbase + (long)row * C_DIM + cc;
    uint4 kv4 = *(const uint4*)(kB + ga);
    uint4 vv4 = *(const uint4*)(vB + ga);
    float wkj = expf(-(float)(T_CH - 1 - row) * etd);
    const ushort* kp = (const ushort*)&kv4;
    const ushort* vp = (const ushort*)&vv4;
#pragma unroll
    for (int e2 = 0; e2 < 8; e2++) {
      kwt_s[(cc + e2) * 136 + row] = f2bf(bf2f(kp[e2]) * wkj);
      vt_s[(cc + e2) * 136 + row] = vp[e2];
    }
  }
  __syncthreads();

  floatx4 accZ[4] = {};
#pragma unroll
  for (int js = 0; js < 128; js += 32) {
    bf16x8 av = *(const bf16x8*)&vt_s[(w * 16 + l16) * 136 + q * 8 + js];
    bf16x8 bk3[4];
#pragma unroll
    for (int kt = 0; kt < 4; kt++)
      bk3[kt] = *(const bf16x8*)&kwt_s[(kt * 16 + l16) * 136 + q * 8 + js];
#pragma unroll
    for (int kt = 0; kt < 4; kt++)
      accZ[kt] = __builtin_amdgcn_mfma_f32_16x16x32_bf16(av, bk3[kt], accZ[kt], 0, 0, 0);
  }
  long zbase = (long)blk * 4096;
#pragma unroll
  for (int kt = 0; kt < 4; kt++)
#pragma unroll
    for (int rg = 0; rg < 4; rg++)
      Zc[zbase + (w * 16 + q * 4 + rg) * 64 + kt * 16 + l16] = f2bf(accZ[kt][rg]);
}

// ============================================================
// 4b) state scan: Sb[bh][n] = state BEFORE chunk n
// ============================================================
__global__ __launch_bounds__(256) void state_scan(
    const ushort* __restrict__ Zc, const float* __restrict__ td,
    ushort* __restrict__ Sb) {
  long tg = (long)blockIdx.x * 256 + threadIdx.x;
  int bh = (int)(tg >> 12);
  int e = (int)(tg & 4095);
  int h = bh & 15;
  float wsf = expf(-128.f * expf(td[h]));
  float s = 0.f;
  long base = (long)bh * N_CH * 4096 + e;
#pragma unroll
  for (int n = 0; n < N_CH; n++) {
    Sb[base + n * 4096] = f2bf(s);
    s = wsf * s + bf2f(Zc[base + n * 4096]);
  }
}

// ============================================================
// 4c) per-chunk output + GroupNorm + *g -> gy (bf16)
// ============================================================
__global__ __launch_bounds__(256) void chunk_out(
    const ushort* __restrict__ rB, const ushort* __restrict__ kB,
    const ushort* __restrict__ vB, const ushort* __restrict__ gBuf,
    const ushort* __restrict__ Sb,
    const float* __restrict__ td, const float* __restrict__ tf,
    const float* __restrict__ lnw, const float* __restrict__ lnb,
    ushort* __restrict__ gy) {
  __shared__ __align__(16) ushort rr_s[128 * 72];
  __shared__ __align__(16) ushort un_s[128 * 136];  // kk then P
  __shared__ __align__(16) ushort vt_s[64 * 136];
  __shared__ __align__(16) ushort z_s[64 * 72];

  int blk = blockIdx.x;
  int bh = blk >> 5, n = blk & 31;
  int b = bh >> 4, h = bh & 15;
  int tid = threadIdx.x;
  int lane = tid & 63, w = tid >> 6;
  int q = lane >> 4, l16 = lane & 15;

  float etd = expf(td[h]);
  float u = tf[h];
  long cbase = ((long)b * TT_DIM + n * T_CH) * C_DIM + h * K_DIM;

#pragma unroll
  for (int it = 0; it < 4; it++) {
    int chunk = it * 256 + tid;
    int row = chunk >> 3;
    int cc = (chunk & 7) * 8;
    long ga = cbase + (long)row * C_DIM + cc;
    *(uint4*)&rr_s[row * 72 + cc] = *(const uint4*)(rB + ga);
    *(uint4*)&un_s[row * 136 + cc] = *(const uint4*)(kB + ga);
    uint4 vv4 = *(const uint4*)(vB + ga);
    const ushort* vp = (const ushort*)&vv4;
#pragma unroll
    for (int e2 = 0; e2 < 8; e2++) vt_s[(cc + e2) * 136 + row] = vp[e2];
  }
  {
    long sbase = (long)blk * 4096;
    int v = tid >> 2, c0 = (tid & 3) * 16;
    *(uint4*)&z_s[v * 72 + c0] = *(const uint4*)(Sb + sbase + v * 64 + c0);
    *(uint4*)&z_s[v * 72 + c0 + 8] = *(const uint4*)(Sb + sbase + v * 64 + c0 + 8);
  }
  __syncthreads();

  floatx4 accA[4][4] = {};
  int ai0 = (w >> 1) * 64, aj0 = (w & 1) * 64;
#pragma unroll
  for (int ks = 0; ks < 64; ks += 32) {
    bf16x8 af[4], bk2[4];
#pragma unroll
    for (int i = 0; i < 4; i++)
      af[i] = *(const bf16x8*)&rr_s[(ai0 + i * 16 + l16) * 72 + q * 8 + ks];
#pragma unroll
    for (int j = 0; j < 4; j++)
      bk2[j] = *(const bf16x8*)&un_s[(aj0 + j * 16 + l16) * 136 + q * 8 + ks];
#pragma unroll
    for (int mi = 0; mi < 4; mi++)
#pragma unroll
      for (int nj = 0; nj < 4; nj++)
        accA[mi][nj] = __builtin_amdgcn_mfma_f32_16x16x32_bf16(
            af[mi], bk2[nj], accA[mi][nj], 0, 0, 0);
  }

  floatx4 accB[2][4] = {};
  int i0 = w * 32;
#pragma unroll
  for (int ks = 0; ks < 64; ks += 32) {
    bf16x8 af2[2], bz[4];
#pragma unroll
    for (int it2 = 0; it2 < 2; it2++)
      af2[it2] = *(const bf16x8*)&rr_s[(i0 + it2 * 16 + l16) * 72 + q * 8 + ks];
#pragma unroll
    for (int vt2 = 0; vt2 < 4; vt2++)
      bz[vt2] = *(const bf16x8*)&z_s[(vt2 * 16 + l16) * 72 + q * 8 + ks];
#pragma unroll
    for (int it2 = 0; it2 < 2; it2++)
#pragma unroll
      for (int vt2 = 0; vt2 < 4; vt2++)
        accB[it2][vt2] = __builtin_amdgcn_mfma_f32_16x16x32_bf16(
            af2[it2], bz[vt2], accB[it2][vt2], 0, 0, 0);
  }
  __syncthreads();

#pragma unroll
  for (int mi = 0; mi < 4; mi++)
#pragma unroll
    for (int nj = 0; nj < 4; nj++)
#pragma unroll
      for (int rg = 0; rg < 4; rg++) {
        int i = ai0 + mi * 16 + q * 4 + rg;
        int j = aj0 + nj * 16 + l16;
        float wv = 0.f;
        if (i > j) wv = expf(-(float)(i - j - 1) * etd);
        else if (i == j) wv = u;
        un_s[i * 136 + j] = f2bf(accA[mi][nj][rg] * wv);
      }
  __syncthreads();

  floatx4 accO[2][4] = {};
#pragma unroll
  for (int js = 0; js < 128; js += 32) {
    bf16x8 af3[2], bv[4];
#pragma unroll
    for (int it2 = 0; it2 < 2; it2++)
      af3[it2] = *(const bf16x8*)&un_s[(i0 + it2 * 16 + l16) * 136 + q * 8 + js];
#pragma unroll
    for (int vt2 = 0; vt2 < 4; vt2++)
      bv[vt2] = *(const bf16x8*)&vt_s[(vt2 * 16 + l16) * 136 + q * 8 + js];
#pragma unroll
    for (int it2 = 0; it2 < 2; it2++)
#pragma unroll
      for (int vt2 = 0; vt2 < 4; vt2++)
        accO[it2][vt2] = __builtin_amdgcn_mfma_f32_16x16x32_bf16(
            af3[it2], bv[vt2], accO[it2][vt2], 0, 0, 0);
  }

#pragma unroll
  for (int it2 = 0; it2 < 2; it2++)
#pragma unroll
    for (int rg = 0; rg < 4; rg++) {
      int i = i0 + it2 * 16 + q * 4 + rg;
      float wbi = expf(-(float)i * etd);
      float vals[4];
      float s1 = 0.f, s2 = 0.f;
#pragma unroll
      for (int vt2 = 0; vt2 < 4; vt2++) {
        float val = accO[it2][vt2][rg] + wbi * accB[it2][vt2][rg];
        vals[vt2] = val; s1 += val; s2 += val * val;
      }
#pragma unroll
      for (int mm = 1; mm < 16; mm <<= 1) {
        s1 += __shfl_xor(s1, mm, 64);
        s2 += __shfl_xor(s2, mm, 64);
      }
      float mu = s1 * (1.f / 64.f);
      float va = s2 * (1.f / 64.f) - mu * mu;
      float rinv = rsqrtf(va + 64.f * 1e-5f);
      long rowg = (long)b * TT_DIM + n * T_CH + i;
#pragma unroll
      for (int vt2 = 0; vt2 < 4; vt2++) {
        int c = h * K_DIM + vt2 * 16 + l16;
        float y = (vals[vt2] - mu) * rinv * lnw[c] + lnb[c];
        float gf = bf2f(gBuf[rowg * C_DIM + c]);
        gy[rowg * C_DIM + c] = f2bf(y * gf);
      }
    }
}

// ============================================================
extern "C" void kernel_launch(void* const* d_in, const int* in_sizes, int n_in,
                              void* d_out, int out_size, void* d_ws,
                              size_t ws_size, hipStream_t stream) {
  const float* xq  = (const float*)d_in[0];
  const float* tmk = (const float*)d_in[1];
  const float* tmv = (const float*)d_in[2];
  const float* tmr = (const float*)d_in[3];
  const float* tmg = (const float*)d_in[4];
  const float* td  = (const float*)d_in[5];
  const float* tf  = (const float*)d_in[6];
  const float* Wr  = (const float*)d_in[7];
  const float* Wk  = (const float*)d_in[8];
  const float* Wv  = (const float*)d_in[9];
  const float* Wg  = (const float*)d_in[10];
  const float* Wo  = (const float*)d_in[11];
  const float* lnw = (const float*)d_in[12];
  const float* lnb = (const float*)d_in[13];

  char* ws = (char*)d_ws;
  const size_t BUF = (size_t)M_ROWS * C_DIM * 2;  // 32 MiB bf16 buffer
  ushort* b0 = (ushort*)(ws + 0 * BUF);  // xr -> later k
  ushort* b1 = (ushort*)(ws + 1 * BUF);  // xk -> later v
  ushort* b2 = (ushort*)(ws + 2 * BUF);  // xv -> later g(silu)
  ushort* b3 = (ushort*)(ws + 3 * BUF);  // xg -> later gy
  ushort* wcv = (ushort*)(ws + 4 * BUF); // 5x 1M bf16 weights (10 MiB)
  const ushort* wr_b = wcv;
  const ushort* wk_b = wcv + (1 << 20);
  const ushort* wv_b = wcv + 2 * (1 << 20);
  const ushort* wg_b = wcv + 3 * (1 << 20);
  const ushort* wo_b = wcv + 4 * (1 << 20);
  ushort* Zc = (ushort*)(ws + 4 * BUF + 5 * (2 << 20));           // 16 MiB
  ushort* Sb = Zc + (size_t)64 * N_CH * 4096;                     // 16 MiB
  ushort* rbuf = (ushort*)d_out;  // bf16 r parked in d_out scratch (32 MiB)

  mix_kernel<<<16384, 256, 0, stream>>>(xq, tmk, tmv, tmr, tmg, b0, b1, b2, b3);
  wconv_kernel<<<5120, 256, 0, stream>>>(Wr, Wk, Wv, Wg, Wo, wcv);

  gemm_bt<0><<<1024, 256, 0, stream>>>(b0, wr_b, rbuf);  // r
  gemm_bt<0><<<1024, 256, 0, stream>>>(b1, wk_b, b0);    // k
  gemm_bt<0><<<1024, 256, 0, stream>>>(b2, wv_b, b1);    // v
  gemm_bt<1><<<1024, 256, 0, stream>>>(b3, wg_b, b2);    // g = silu(xg@Wg^T)

  chunk_state<<<2048, 256, 0, stream>>>(b0, b1, td, Zc);
  state_scan<<<1024, 256, 0, stream>>>(Zc, td, Sb);
  chunk_out<<<2048, 256, 0, stream>>>(rbuf, b0, b1, b2, Sb, td, tf, lnw, lnb, b3);

  gemm_bt<2><<<1024, 256, 0, stream>>>(b3, wo_b, (float*)d_out);  // fp32 out
}